// Round 1
// baseline (349.653 us; speedup 1.0000x reference)
//
#include <hip/hip_runtime.h>

#define NUM_CLS   131072
#define NUM_NODE  70
#define DRUG_NUM  38
#define NSEG      140
#define ROWLEN    70
#define FEA       128
#define MTOT      524288
#define BATCH     8192
#define NB1       512           // partial-sum blocks for the segment pass
#define SEGW      (NSEG*ROWLEN + NSEG)   // 9940 floats per partial block

// ---------------- K1: per-block partial segment sums of DTH rows ----------------
__global__ __launch_bounds__(256) void seg_partial_k(
    const float* __restrict__ dth_cls, const float* __restrict__ dth_dc,
    const int* __restrict__ he_node, const int* __restrict__ he_edge,
    float* __restrict__ partial)
{
  __shared__ float acc[NSEG * ROWLEN];
  __shared__ float cnt[NSEG];
  const int tid = threadIdx.x;
  for (int i = tid; i < NSEG * ROWLEN; i += 256) acc[i] = 0.f;
  for (int i = tid; i < NSEG; i += 256) cnt[i] = 0.f;
  __syncthreads();

  const int lane   = tid & 31;
  const int ggroup = blockIdx.x * 8 + (tid >> 5);   // 32-lane groups
  const int ngroups = NB1 * 8;
  for (int e = ggroup; e < MTOT; e += ngroups) {
    const int node = he_node[e];
    const int edge = he_edge[e];
    const int isdc = (edge >= NUM_CLS);
    const int seg  = node * 2 + isdc;
    const float* row = isdc ? (dth_dc + (size_t)(edge - NUM_CLS) * ROWLEN)
                            : (dth_cls + (size_t)edge * ROWLEN);
    for (int c = lane; c < ROWLEN; c += 32)
      atomicAdd(&acc[seg * ROWLEN + c], row[c]);
    if (lane == 0) atomicAdd(&cnt[seg], 1.f);
  }
  __syncthreads();

  float* dst = partial + (size_t)blockIdx.x * SEGW;
  for (int i = tid; i < NSEG * ROWLEN; i += 256) dst[i] = acc[i];
  for (int i = tid; i < NSEG; i += 256) dst[NSEG * ROWLEN + i] = cnt[i];
}

// ---------------- K2: reduce partials (deterministic order) ----------------
__global__ __launch_bounds__(256) void seg_reduce_k(
    const float* __restrict__ partial, float* __restrict__ rowsum,
    float* __restrict__ cnt)
{
  const int j = blockIdx.x * 256 + threadIdx.x;
  if (j >= SEGW) return;
  float s = 0.f;
  for (int b = 0; b < NB1; ++b) s += partial[(size_t)b * SEGW + j];
  if (j < NSEG * ROWLEN) rowsum[j] = s;
  else                   cnt[j - NSEG * ROWLEN] = s;
}

// ---------------- K3a: edge_group[s][c] = (rowsum[s] . merge[:,c]) / max(cnt,1) ----
__global__ __launch_bounds__(128) void edge_group_k(
    const float* __restrict__ rowsum, const float* __restrict__ cnt,
    const float* __restrict__ dE, const float* __restrict__ cE,
    float* __restrict__ edge_group)
{
  __shared__ float rs[ROWLEN];
  const int s = blockIdx.x, c = threadIdx.x;
  if (c < ROWLEN) rs[c] = rowsum[s * ROWLEN + c];
  __syncthreads();
  float a = 0.f;
  #pragma unroll
  for (int k = 0; k < DRUG_NUM; ++k) a += rs[k] * dE[k * FEA + c];
  #pragma unroll
  for (int k = DRUG_NUM; k < NUM_NODE; ++k) a += rs[k] * cE[(k - DRUG_NUM) * FEA + c];
  edge_group[s * FEA + c] = a / fmaxf(cnt[s], 1.f);
}

// ---------------- K3b: fc / projections / head-softmax / node_rep ----------------
__global__ __launch_bounds__(128) void node_rep_k(
    const float* __restrict__ edge_group, const float* __restrict__ dE,
    const float* __restrict__ cE, const float* __restrict__ node_proj,
    const float* __restrict__ edge_proj, const float* __restrict__ fc_w,
    const float* __restrict__ fc_b, float* __restrict__ node_rep)
{
  __shared__ float fw[FEA][FEA + 1];     // fc_w staged, padded vs bank conflicts
  __shared__ float eg[2][FEA];
  __shared__ float mg[FEA];
  __shared__ float nm[FEA];
  __shared__ float em[2][FEA];
  __shared__ float ef[2][FEA];
  __shared__ float sc[4][2];
  __shared__ float wgt[4][2];

  const int n = blockIdx.x, c = threadIdx.x;
  const int isdrug = (n < DRUG_NUM);
  eg[0][c] = edge_group[(n * 2 + 0) * FEA + c];
  eg[1][c] = edge_group[(n * 2 + 1) * FEA + c];
  mg[c] = isdrug ? dE[n * FEA + c] : cE[(n - DRUG_NUM) * FEA + c];
  for (int r = 0; r < FEA; ++r) fw[r][c] = fc_w[r * FEA + c];
  __syncthreads();

  // edge_feat = relu(edge_group @ fc_w^T + fc_b)
  for (int e = 0; e < 2; ++e) {
    float a = fc_b[c];
    #pragma unroll 8
    for (int k = 0; k < FEA; ++k) a += eg[e][k] * fw[c][k];
    ef[e][c] = fmaxf(a, 0.f);
  }
  // node_m = merge_row @ node_proj[p]
  {
    const float* P = node_proj + (size_t)(isdrug ? 0 : 1) * FEA * FEA;
    float a = 0.f;
    #pragma unroll 8
    for (int k = 0; k < FEA; ++k) a += mg[k] * P[k * FEA + c];
    nm[c] = a;
  }
  // edge_m[e] = edge_group[e] @ edge_proj[pe]
  for (int e = 0; e < 2; ++e) {
    const float* P = edge_proj + (size_t)((isdrug ? 0 : 2) + e) * FEA * FEA;
    float a = 0.f;
    #pragma unroll 8
    for (int k = 0; k < FEA; ++k) a += eg[e][k] * P[k * FEA + c];
    em[e][c] = a;
  }
  __syncthreads();

  if (c < 8) {   // scores[h][e] = (q[h].k[e][h]) / sqrt(32)
    const int h = c >> 1, e = c & 1;
    float s = 0.f;
    #pragma unroll
    for (int d = 0; d < 32; ++d) s += nm[h * 32 + d] * em[e][h * 32 + d];
    sc[h][e] = s * 0.17677669529663687f;
  }
  __syncthreads();
  if (c < 2) {   // softmax over the HEAD axis (faithful to reference)
    const int e = c;
    const float mx = fmaxf(fmaxf(sc[0][e], sc[1][e]), fmaxf(sc[2][e], sc[3][e]));
    const float t0 = expf(sc[0][e] - mx), t1 = expf(sc[1][e] - mx);
    const float t2 = expf(sc[2][e] - mx), t3 = expf(sc[3][e] - mx);
    const float inv = 1.f / (t0 + t1 + t2 + t3);
    wgt[0][e] = t0 * inv; wgt[1][e] = t1 * inv;
    wgt[2][e] = t2 * inv; wgt[3][e] = t3 * inv;
  }
  __syncthreads();

  const int h = c >> 5;
  const float v = fmaxf(wgt[h][0] * ef[0][c], 0.f) + fmaxf(wgt[h][1] * ef[1][c], 0.f);
  node_rep[n * FEA + c] = v;
}

// ---------------- K4a: gather + BN (eval) -> emb[8192][384] ----------------
__global__ __launch_bounds__(384) void emb_bn_k(
    const float* __restrict__ node_rep, const int* __restrict__ index,
    const float* __restrict__ gam, const float* __restrict__ bet,
    const float* __restrict__ mean, const float* __restrict__ var,
    float* __restrict__ emb)
{
  const int b = blockIdx.x, j = threadIdx.x;
  const int part = j >> 7, cc = j & 127;
  const int idx = index[b * 3 + part];
  float v = node_rep[idx * FEA + cc];
  v = (v - mean[j]) * rsqrtf(var[j] + 1e-5f) * gam[j] + bet[j];
  emb[(size_t)b * 384 + j] = v;
}

// ---------------- K4b/c: C = lrelu(A @ W^T + bias), 64x64 tile, 4x4 microtile ----
__global__ __launch_bounds__(256) void gemm_nt_k(
    const float* __restrict__ A,     // [M,K]
    const float* __restrict__ W,     // [N,K]
    const float* __restrict__ bias,  // [N]
    float* __restrict__ C,           // [M,N]
    int M, int N, int K, int do_lrelu)
{
  __shared__ float As[16][68];   // [kk][row], pad 68 -> conflict-free scatter
  __shared__ float Ws[16][68];
  const int tid = threadIdx.x;
  const int tx = tid & 15, ty = tid >> 4;
  const int row0 = blockIdx.y * 64, col0 = blockIdx.x * 64;
  const int lr = tid >> 2;            // 0..63
  const int lk = (tid & 3) << 2;      // 0,4,8,12
  float acc[4][4] = {{0.f}};

  for (int k0 = 0; k0 < K; k0 += 16) {
    const float4 av = *(const float4*)(A + (size_t)(row0 + lr) * K + k0 + lk);
    const float4 wv = *(const float4*)(W + (size_t)(col0 + lr) * K + k0 + lk);
    __syncthreads();
    As[lk + 0][lr] = av.x; As[lk + 1][lr] = av.y; As[lk + 2][lr] = av.z; As[lk + 3][lr] = av.w;
    Ws[lk + 0][lr] = wv.x; Ws[lk + 1][lr] = wv.y; Ws[lk + 2][lr] = wv.z; Ws[lk + 3][lr] = wv.w;
    __syncthreads();
    #pragma unroll
    for (int kk = 0; kk < 16; ++kk) {
      const float4 a = *(const float4*)&As[kk][ty * 4];
      const float4 b = *(const float4*)&Ws[kk][tx * 4];
      acc[0][0] += a.x * b.x; acc[0][1] += a.x * b.y; acc[0][2] += a.x * b.z; acc[0][3] += a.x * b.w;
      acc[1][0] += a.y * b.x; acc[1][1] += a.y * b.y; acc[1][2] += a.y * b.z; acc[1][3] += a.y * b.w;
      acc[2][0] += a.z * b.x; acc[2][1] += a.z * b.y; acc[2][2] += a.z * b.z; acc[2][3] += a.z * b.w;
      acc[3][0] += a.w * b.x; acc[3][1] += a.w * b.y; acc[3][2] += a.w * b.z; acc[3][3] += a.w * b.w;
    }
  }

  const float4 bv = *(const float4*)(bias + col0 + tx * 4);
  #pragma unroll
  for (int i = 0; i < 4; ++i) {
    const int r = row0 + ty * 4 + i;
    float4 o;
    o.x = acc[i][0] + bv.x; o.y = acc[i][1] + bv.y;
    o.z = acc[i][2] + bv.z; o.w = acc[i][3] + bv.w;
    if (do_lrelu) {
      o.x = o.x > 0.f ? o.x : 0.5f * o.x; o.y = o.y > 0.f ? o.y : 0.5f * o.y;
      o.z = o.z > 0.f ? o.z : 0.5f * o.z; o.w = o.w > 0.f ? o.w : 0.5f * o.w;
    }
    *(float4*)(C + (size_t)r * N + col0 + tx * 4) = o;
  }
}

// ---------------- K4d: out0 = sigmoid(h @ w3 + b3) ----------------
__global__ __launch_bounds__(256) void lin3_k(
    const float* __restrict__ H, const float* __restrict__ w3,
    const float* __restrict__ b3, float* __restrict__ out)
{
  const int row = blockIdx.x * 4 + (threadIdx.x >> 6);
  const int lane = threadIdx.x & 63;
  const float4 h = *(const float4*)(H + (size_t)row * 256 + lane * 4);
  const float4 w = *(const float4*)(w3 + lane * 4);
  float v = h.x * w.x + h.y * w.y + h.z * w.z + h.w * w.w;
  #pragma unroll
  for (int off = 32; off; off >>= 1) v += __shfl_down(v, off);
  if (lane == 0) out[row] = 1.f / (1.f + expf(-(v + b3[0])));
}

extern "C" void kernel_launch(void* const* d_in, const int* in_sizes, int n_in,
                              void* d_out, int out_size, void* d_ws, size_t ws_size,
                              hipStream_t stream) {
  const float* dth_cls  = (const float*)d_in[2];
  const float* dth_dc   = (const float*)d_in[3];
  const int*   he_node  = (const int*)d_in[4];
  const int*   he_edge  = (const int*)d_in[5];
  const int*   index    = (const int*)d_in[7];
  const float* dE       = (const float*)d_in[8];
  const float* cE       = (const float*)d_in[9];
  const float* node_proj= (const float*)d_in[10];
  const float* edge_proj= (const float*)d_in[11];
  const float* fc_w     = (const float*)d_in[12];
  const float* fc_b     = (const float*)d_in[13];
  const float* bn_g     = (const float*)d_in[14];
  const float* bn_b     = (const float*)d_in[15];
  const float* bn_m     = (const float*)d_in[16];
  const float* bn_v     = (const float*)d_in[17];
  const float* w1       = (const float*)d_in[18];
  const float* b1       = (const float*)d_in[19];
  const float* w2       = (const float*)d_in[20];
  const float* b2       = (const float*)d_in[21];
  const float* w3       = (const float*)d_in[22];
  const float* b3       = (const float*)d_in[23];

  float* out0 = (float*)d_out;
  float* hout = out0 + BATCH;                 // [8192,256], second output

  float* ws        = (float*)d_ws;            // all offsets 16-float aligned
  float* rowsum    = ws + 0;                  // 9800
  float* cnt       = ws + 9856;               // 140
  float* edge_group= ws + 10048;              // 140*128
  float* node_rep  = ws + 28032;              // 70*128
  float* emb       = ws + 37056;              // 8192*384
  float* h1        = ws + 3182784;            // 8192*512   (end: 7,377,088 floats)
  float* partial   = ws + 37056;              // aliases emb region (consumed before emb written)

  seg_partial_k<<<NB1, 256, 0, stream>>>(dth_cls, dth_dc, he_node, he_edge, partial);
  seg_reduce_k<<<(SEGW + 255) / 256, 256, 0, stream>>>(partial, rowsum, cnt);
  edge_group_k<<<NSEG, 128, 0, stream>>>(rowsum, cnt, dE, cE, edge_group);
  node_rep_k<<<NUM_NODE, 128, 0, stream>>>(edge_group, dE, cE, node_proj, edge_proj,
                                           fc_w, fc_b, node_rep);
  emb_bn_k<<<BATCH, 384, 0, stream>>>(node_rep, index, bn_g, bn_b, bn_m, bn_v, emb);
  gemm_nt_k<<<dim3(512 / 64, BATCH / 64), 256, 0, stream>>>(emb, w1, b1, h1,
                                                            BATCH, 512, 384, 1);
  gemm_nt_k<<<dim3(256 / 64, BATCH / 64), 256, 0, stream>>>(h1, w2, b2, hout,
                                                            BATCH, 256, 512, 1);
  lin3_k<<<BATCH / 4, 256, 0, stream>>>(hout, w3, b3, out0);
}